// Round 11
// baseline (281.368 us; speedup 1.0000x reference)
//
#include <hip/hip_runtime.h>
#include <stdint.h>

#define B_  4
#define S_  2048
#define D_  1024
#define H_  16
#define DK_ 64
#define M_  (B_ * S_)

typedef __attribute__((ext_vector_type(8))) short bf16x8;
typedef __attribute__((ext_vector_type(4))) float f32x4;

// Q pre-scale: 1/sqrt(64) * log2(e)  (scores land in exp2 domain)
#define QSCALE 0.1803368801111204f

__device__ __forceinline__ uint16_t f2bf(float f) {
    uint32_t u = __builtin_bit_cast(uint32_t, f);
    u = (u + 0x7FFFu + ((u >> 16) & 1u)) >> 16;   // round-to-nearest-even
    return (uint16_t)u;
}

// pack two f32 -> bf16x2 (lo in low half), round-half-up, 3 VALU ops
__device__ __forceinline__ uint32_t pk2bf(float hi, float lo) {
    uint32_t a = __builtin_bit_cast(uint32_t, hi) + 0x8000u;
    uint32_t b = __builtin_bit_cast(uint32_t, lo) + 0x8000u;
    return __builtin_amdgcn_perm(a, b, 0x07060302u);
}

// direct global->LDS, 16 B per lane, wave-uniform LDS base (+ lane*16 by HW)
__device__ __forceinline__ void gload_lds16(const uint16_t* g, uint16_t* l) {
    __builtin_amdgcn_global_load_lds(
        (const __attribute__((address_space(1))) unsigned int*)g,
        (__attribute__((address_space(3))) unsigned int*)l,
        16, 0, 0);
}

// ---------------------------------------------------------------------------
// Fused prep: fp32->bf16 convert of x, transpose+convert of Wq/Wk/Wv, and
// transpose+convert of Wo — one launch, dispatched on blockIdx.x.
// ---------------------------------------------------------------------------
__global__ __launch_bounds__(256) void prep_kernel(
    const float* __restrict__ x,
    const float* __restrict__ Wq, const float* __restrict__ Wk,
    const float* __restrict__ Wv, const float* __restrict__ Wo,
    uint16_t* __restrict__ xb, uint16_t* __restrict__ Wt,
    uint16_t* __restrict__ Wot)
{
    __shared__ __align__(16) uint16_t tile[64][72];
    const int bid = blockIdx.x;
    const int t = threadIdx.x;

    if (bid < 4096) {              // ---- cvt x -> xb, 8 elems/thread
        int i = (bid * 256 + t) * 8;
        float4 a = *(const float4*)&x[i];
        float4 b = *(const float4*)&x[i + 4];
        uint16_t o[8] = {f2bf(a.x), f2bf(a.y), f2bf(a.z), f2bf(a.w),
                         f2bf(b.x), f2bf(b.y), f2bf(b.z), f2bf(b.w)};
        *(uint4*)&xb[i] = *(const uint4*)o;
        return;
    }

    const int lr = t >> 2, lc = (t & 3) * 16;
    const int oc = t >> 2, orr = (t & 3) * 16;

    if (bid < 4096 + 768) {        // ---- Wq/Wk/Wv: [1024][64] -> [dk][d] bf16
        const int zz = bid - 4096;
        const int z = zz >> 4, bx = zz & 15;       // z: 0..47 matrix, bx: d-tile
        const int sel = z >> 4, mat = z & 15;
        const float* base = (sel == 0) ? Wq : (sel == 1) ? Wk : Wv;
        const float* inm = base + (size_t)mat * 1024 * 64;
        uint16_t* outm = Wt + (size_t)z * 65536;
        const int r0 = bx * 64;
        uint16_t tmp[16];
        #pragma unroll
        for (int j = 0; j < 16; j += 4) {
            float4 v = *(const float4*)&inm[(size_t)(r0 + lr) * 64 + lc + j];
            tmp[j] = f2bf(v.x); tmp[j + 1] = f2bf(v.y); tmp[j + 2] = f2bf(v.z); tmp[j + 3] = f2bf(v.w);
        }
        *(uint4*)&tile[lr][lc]     = ((const uint4*)tmp)[0];
        *(uint4*)&tile[lr][lc + 8] = ((const uint4*)tmp)[1];
        __syncthreads();
        uint16_t ot[16];
        #pragma unroll
        for (int j = 0; j < 16; ++j) ot[j] = tile[orr + j][oc];
        *(uint4*)&outm[(size_t)oc * 1024 + r0 + orr]     = ((const uint4*)ot)[0];
        *(uint4*)&outm[(size_t)oc * 1024 + r0 + orr + 8] = ((const uint4*)ot)[1];
    } else {                       // ---- Wo: [1024][1024] -> [n][d] bf16
        const int zz = bid - 4864;
        const int bx = zz & 15, by = zz >> 4;
        const int r0 = bx * 64, c0 = by * 64;
        uint16_t tmp[16];
        #pragma unroll
        for (int j = 0; j < 16; j += 4) {
            float4 v = *(const float4*)&Wo[(size_t)(r0 + lr) * 1024 + c0 + lc + j];
            tmp[j] = f2bf(v.x); tmp[j + 1] = f2bf(v.y); tmp[j + 2] = f2bf(v.z); tmp[j + 3] = f2bf(v.w);
        }
        *(uint4*)&tile[lr][lc]     = ((const uint4*)tmp)[0];
        *(uint4*)&tile[lr][lc + 8] = ((const uint4*)tmp)[1];
        __syncthreads();
        uint16_t ot[16];
        #pragma unroll
        for (int j = 0; j < 16; ++j) ot[j] = tile[orr + j][oc];
        *(uint4*)&Wot[(size_t)(c0 + oc) * 1024 + r0 + orr]     = ((const uint4*)ot)[0];
        *(uint4*)&Wot[(size_t)(c0 + oc) * 1024 + r0 + orr + 8] = ((const uint4*)ot)[1];
    }
}

// ---------------------------------------------------------------------------
// QKV projection, MFMA. C[128 x 128] per block; 4 waves in 2x2, 64x64/wave.
// T3 minimum-2-phase: double-buffered [2][128][32] LDS (BK=32, 32 KiB),
// gload_lds prefetch of tile kt+1 issued BEFORE compute of tile kt, ONE
// __syncthreads per K-step (its implicit vmcnt(0) lands after compute, so
// the DMA latency hides under the MFMAs). Both-sides XOR swizzle:
//   LDS[r][c] = G[r][c ^ (r&3)]  (4 chunks of 16B per 64B row)
//   read chunk = quad ^ (ll&3)   -> 8 lanes per 4-bank group (free 2-way)
// Zero ds_writes, zero exposed drain. Q pre-scaled. V transposed [bh][dk][s].
// ---------------------------------------------------------------------------
__global__ __launch_bounds__(256) void qkv_mfma_kernel(
    const uint16_t* __restrict__ xb, const uint16_t* __restrict__ Wt,
    const float* __restrict__ bq, const float* __restrict__ bk, const float* __restrict__ bv,
    uint16_t* __restrict__ Q, uint16_t* __restrict__ K, uint16_t* __restrict__ V)
{
    __shared__ __align__(16) uint16_t As[2][128][32];
    __shared__ __align__(16) uint16_t Bs[2][128][32];
    const int tid = threadIdx.x;
    const int nb = blockIdx.x;                  // 0..23
    const int sel = nb >> 3, npair = nb & 7;
    const int m0 = blockIdx.y * 128;
    const int lane = tid & 63, w = tid >> 6;
    const int wr = w >> 1, wc = w & 1;
    const int ll = lane & 15, quad = lane >> 4;

    const uint16_t* Bg = Wt + (size_t)nb * 128 * 1024;
    const float* bias = (sel == 0) ? bq : (sel == 1) ? bk : bv;

    // staging: each gload_lds covers 16 rows x 64 B. Wave w: rows [w*32,+32)
    // via 2 issues. lane: row += lane>>2, 16B chunk pre-swizzled.
    const int srow = lane >> 2;                  // 0..15
    const int scg  = (lane & 3) ^ (srow & 3);    // pre-swizzled chunk
    const uint16_t* agp = &xb[(size_t)(m0 + w * 32 + srow) * 1024 + scg * 8];
    const uint16_t* bgp = &Bg[(size_t)(w * 32 + srow) * 1024 + scg * 8];

    // read-side swizzled chunk (element offset); read rows have row&3 == ll&3
    const int rc = (quad ^ (ll & 3)) * 8;

    f32x4 acc[4][4];
    const f32x4 zz = {0.f, 0.f, 0.f, 0.f};
    #pragma unroll
    for (int i = 0; i < 4; ++i)
        #pragma unroll
        for (int j = 0; j < 4; ++j) acc[i][j] = zz;

    // prologue: stage k-tile 0 into buffer 0
    gload_lds16(agp,             &As[0][w * 32][0]);
    gload_lds16(agp + 16 * 1024, &As[0][w * 32 + 16][0]);
    gload_lds16(bgp,             &Bs[0][w * 32][0]);
    gload_lds16(bgp + 16 * 1024, &Bs[0][w * 32 + 16][0]);
    __syncthreads();                       // buffer 0 ready

    for (int kt = 0; kt < 32; ++kt) {
        const int cur = kt & 1;
        if (kt + 1 < 32) {                 // issue next tile into other buffer
            const int k0 = (kt + 1) * 32;  // safe: all waves done reading it
            gload_lds16(agp + k0,             &As[cur ^ 1][w * 32][0]);
            gload_lds16(agp + 16 * 1024 + k0, &As[cur ^ 1][w * 32 + 16][0]);
            gload_lds16(bgp + k0,             &Bs[cur ^ 1][w * 32][0]);
            gload_lds16(bgp + 16 * 1024 + k0, &Bs[cur ^ 1][w * 32 + 16][0]);
        }
        bf16x8 af[4], bfv[4];
        #pragma unroll
        for (int mt = 0; mt < 4; ++mt)
            af[mt] = *(const bf16x8*)&As[cur][wr * 64 + mt * 16 + ll][rc];
        #pragma unroll
        for (int nt = 0; nt < 4; ++nt)
            bfv[nt] = *(const bf16x8*)&Bs[cur][wc * 64 + nt * 16 + ll][rc];
        __builtin_amdgcn_s_setprio(1);
        #pragma unroll
        for (int mt = 0; mt < 4; ++mt)
            #pragma unroll
            for (int nt = 0; nt < 4; ++nt)
                acc[mt][nt] = __builtin_amdgcn_mfma_f32_16x16x32_bf16(af[mt], bfv[nt], acc[mt][nt], 0, 0, 0);
        __builtin_amdgcn_s_setprio(0);
        __syncthreads();   // drains prefetch (vmcnt 0) + all reads of cur done
    }

    if (sel == 2) {
        #pragma unroll
        for (int nt = 0; nt < 4; ++nt) {
            const int nl = wc * 64 + nt * 16 + ll;
            const int hh = npair * 2 + (nl >> 6);
            const int dk = nl & 63;
            const float bval = bias[npair * 128 + nl];
            #pragma unroll
            for (int mt = 0; mt < 4; ++mt) {
                int m = m0 + wr * 64 + mt * 16 + quad * 4;
                int b = m >> 11, s = m & 2047;
                uint2 pv;
                pv.x = pk2bf(acc[mt][nt][1] + bval, acc[mt][nt][0] + bval);
                pv.y = pk2bf(acc[mt][nt][3] + bval, acc[mt][nt][2] + bval);
                *(uint2*)&V[((size_t)(b * 16 + hh) * 64 + dk) * 2048 + s] = pv;
            }
        }
    } else {
        uint16_t* Out = (sel == 0) ? Q : K;
        const float qs = (sel == 0) ? QSCALE : 1.0f;
        #pragma unroll
        for (int nt = 0; nt < 4; ++nt) {
            const int nl = wc * 64 + nt * 16 + ll;
            const int hh = npair * 2 + (nl >> 6);
            const int dk = nl & 63;
            const float bval = bias[npair * 128 + nl];
            #pragma unroll
            for (int mt = 0; mt < 4; ++mt) {
                #pragma unroll
                for (int r = 0; r < 4; ++r) {
                    int m = m0 + wr * 64 + mt * 16 + quad * 4 + r;
                    int b = m >> 11, s = m & 2047;
                    float v = (acc[mt][nt][r] + bval) * qs;
                    Out[((size_t)(b * 16 + hh) * 2048 + s) * 64 + dk] = f2bf(v);
                }
            }
        }
    }
}

// ---------------------------------------------------------------------------
// Flash attention, MFMA, S^T = K·Q^T. 128-row q-blocks; block pairs q-tiles
// (15-p, p). KV tiles 128 wide, uniform trip counts, mask only on diagonal
// tile. K/V staged in LDS with T14 async-stage. PV in two 64-wide halves
// time-sharing Ps (wave-private). LDS 54,272 B. exp2-domain softmax.
// ---------------------------------------------------------------------------
__global__ __launch_bounds__(256) void attn_mfma_kernel(
    const uint16_t* __restrict__ Q, const uint16_t* __restrict__ K,
    const uint16_t* __restrict__ Vg, uint16_t* __restrict__ CAT)
{
    __shared__ __align__(16) uint16_t Ks[128][72];
    __shared__ __align__(16) uint16_t Vt[64][136];
    __shared__ __align__(16) uint16_t Ps[128][72];

    const int tid = threadIdx.x;
    const int lane = tid & 63, w = tid >> 6;
    const int ll = lane & 15, quad = lane >> 4;
    const int p = blockIdx.x;          // 0..7
    const int bh = blockIdx.y;
    const int b = bh >> 4, h = bh & 15;

    const uint16_t* Qbh = Q + (size_t)bh * S_ * 64;
    const uint16_t* Kbh = K + (size_t)bh * S_ * 64;
    const uint16_t* Vbh = Vg + (size_t)bh * 64 * S_;   // [dk][s]
    uint16_t* Cbh = CAT + (size_t)b * 2048 * 1024 + h * 64;

    // K staging: 2 threads/row, 64 B each
    const int ksr = tid >> 1, ksc = (tid & 1) * 32;
    // V staging: 4 threads/row, 64 B each
    const int vsr = tid >> 2, vsc = (tid & 3) * 32;
    const uint16_t* kgp = &Kbh[(size_t)ksr * 64 + ksc];       // + tb*64
    const uint16_t* vgp = &Vbh[(size_t)vsr * 2048 + vsc];     // + tb

    // ones B-fragment: B[k][0] = 1 -> row sums land in output col 0
    bf16x8 onesf;
    #pragma unroll
    for (int j = 0; j < 8; ++j) onesf[j] = (ll == 0) ? (short)0x3F80 : (short)0;

    const f32x4 zz = {0.f, 0.f, 0.f, 0.f};

    #pragma unroll 1
    for (int phase = 0; phase < 2; ++phase) {
        const int qtb = (phase == 0) ? (15 - p) : p;
        const int q0 = qtb * 128;
        const int qw = q0 + w * 32;     // this wave's q rows [qw, qw+32)

        bf16x8 qf[2][2];
        #pragma unroll
        for (int mt = 0; mt < 2; ++mt)
            #pragma unroll
            for (int ks = 0; ks < 2; ++ks)
                qf[mt][ks] = *(const bf16x8*)&Qbh[(size_t)(qw + mt * 16 + ll) * 64 + ks * 32 + quad * 8];

        f32x4 oacc[2][4];
        f32x4 lacc[2];
        #pragma unroll
        for (int i = 0; i < 2; ++i) {
            lacc[i] = zz;
            #pragma unroll
            for (int j = 0; j < 4; ++j) oacc[i][j] = zz;
        }

        const int nkt = qtb + 1;        // uniform across waves

        // prologue: tile 0 K/V loads into regs (global->reg, no LDS touch)
        uint4 kr0 = *(const uint4*)(kgp),      kr1 = *(const uint4*)(kgp + 8);
        uint4 kr2 = *(const uint4*)(kgp + 16), kr3 = *(const uint4*)(kgp + 24);
        uint4 vr0 = *(const uint4*)(vgp),      vr1 = *(const uint4*)(vgp + 8);
        uint4 vr2 = *(const uint4*)(vgp + 16), vr3 = *(const uint4*)(vgp + 24);

        #pragma unroll 1
        for (int kt = 0; kt < nkt; ++kt) {
            const int tb = kt * 128;
            __syncthreads();   // all waves done reading Ks/Vt of prior tile
            *(uint4*)&Ks[ksr][ksc]      = kr0;
            *(uint4*)&Ks[ksr][ksc + 8]  = kr1;
            *(uint4*)&Ks[ksr][ksc + 16] = kr2;
            *(uint4*)&Ks[ksr][ksc + 24] = kr3;
            *(uint4*)&Vt[vsr][vsc]      = vr0;
            *(uint4*)&Vt[vsr][vsc + 8]  = vr1;
            *(uint4*)&Vt[vsr][vsc + 16] = vr2;
            *(uint4*)&Vt[vsr][vsc + 24] = vr3;
            __syncthreads();

            if (kt + 1 < nkt) {     // issue next-tile loads early (overlap)
                const uint16_t* kg = kgp + (size_t)(tb + 128) * 64;
                const uint16_t* vg = vgp + tb + 128;
                kr0 = *(const uint4*)(kg);      kr1 = *(const uint4*)(kg + 8);
                kr2 = *(const uint4*)(kg + 16); kr3 = *(const uint4*)(kg + 24);
                vr0 = *(const uint4*)(vg);      vr1 = *(const uint4*)(vg + 8);
                vr2 = *(const uint4*)(vg + 16); vr3 = *(const uint4*)(vg + 24);
            }

            // S^T = K·Q^T  (M = t rows of K, N = q), 8 t-subtiles
            f32x4 sacc[8][2];
            #pragma unroll
            for (int i = 0; i < 8; ++i)
                #pragma unroll
                for (int j = 0; j < 2; ++j) sacc[i][j] = zz;
            #pragma unroll
            for (int ks = 0; ks < 2; ++ks) {
                #pragma unroll
                for (int tt = 0; tt < 8; ++tt) {
                    bf16x8 kf = *(const bf16x8*)&Ks[tt * 16 + ll][ks * 32 + quad * 8];
                    #pragma unroll
                    for (int mt = 0; mt < 2; ++mt)
                        sacc[tt][mt] = __builtin_amdgcn_mfma_f32_16x16x32_bf16(kf, qf[mt][ks], sacc[tt][mt], 0, 0, 0);
                }
            }

            // mask (diagonal tile only) + exp2
            const bool needMask = (kt == nkt - 1);
            #pragma unroll
            for (int mt = 0; mt < 2; ++mt) {
                const int qg = qw + mt * 16 + ll;
                #pragma unroll
                for (int tt = 0; tt < 8; ++tt) {
                    #pragma unroll
                    for (int r = 0; r < 4; ++r) {
                        float v = sacc[tt][mt][r];
                        if (needMask) {
                            int tg = tb + tt * 16 + quad * 4 + r;
                            v = (tg > qg) ? -1e30f : v;
                        }
                        sacc[tt][mt][r] = __builtin_amdgcn_exp2f(v);
                    }
                }
            }

            // PV in two 64-wide halves, time-sharing Ps (wave-private rows;
            // per-wave in-order DS pipeline makes pack->read->repack safe).
            #pragma unroll
            for (int half = 0; half < 2; ++half) {
                #pragma unroll
                for (int mt = 0; mt < 2; ++mt) {
                    #pragma unroll
                    for (int t4 = 0; t4 < 4; ++t4) {
                        const int tt = half * 4 + t4;
                        uint2 pv;
                        pv.x = pk2bf(sacc[tt][mt][1], sacc[tt][mt][0]);
                        pv.y = pk2bf(sacc[tt][mt][3], sacc[tt][mt][2]);
                        *(uint2*)&Ps[w * 32 + mt * 16 + ll][t4 * 16 + quad * 4] = pv;
                    }
                }
                #pragma unroll
                for (int ks2 = 0; ks2 < 2; ++ks2) {
                    bf16x8 pf[2], vf[4];
                    #pragma unroll
                    for (int mt = 0; mt < 2; ++mt)
                        pf[mt] = *(const bf16x8*)&Ps[w * 32 + mt * 16 + ll][ks2 * 32 + quad * 8];
                    #pragma unroll
                    for (int nt = 0; nt < 4; ++nt)
                        vf[nt] = *(const bf16x8*)&Vt[nt * 16 + ll][half * 64 + ks2 * 32 + quad * 8];
                    #pragma unroll
                    for (int mt = 0; mt < 2; ++mt) {
                        lacc[mt] = __builtin_amdgcn_mfma_f32_16x16x32_bf16(pf[mt], onesf, lacc[mt], 0, 0, 0);
                        #pragma unroll
                        for (int nt = 0; nt < 4; ++nt)
                            oacc[mt][nt] = __builtin_amdgcn_mfma_f32_16x16x32_bf16(pf[mt], vf[nt], oacc[mt][nt], 0, 0, 0);
                    }
                }
            }
        }

        // epilogue: l lives in lanes ll==0 (output col 0); broadcast within
        // each quad group via shfl, then scale + store
        #pragma unroll
        for (int mt = 0; mt < 2; ++mt) {
            f32x4 li;
            #pragma unroll
            for (int r = 0; r < 4; ++r)
                li[r] = 1.0f / __shfl(lacc[mt][r], lane & 48);
            #pragma unroll
            for (int r = 0; r < 4; ++r) {
                int q = qw + mt * 16 + quad * 4 + r;
                #pragma unroll
                for (int nt = 0; nt < 4; ++nt) {
                    float v = oacc[mt][nt][r] * li[r];
                    Cbh[(size_t)q * 1024 + nt * 16 + ll] = f2bf(v);
                }
            }
        }
        // next phase's first __syncthreads (top of kt loop) guards restaging
    }
}

// ---------------------------------------------------------------------------
// Output projection: out = CAT(bf16) @ Wo + bo, fp32 out. 128x128 tiles.
// Register-staged LDS (padded [128][72]) with T14 async-stage.
// ---------------------------------------------------------------------------
__global__ __launch_bounds__(256) void oproj_mfma_kernel(
    const uint16_t* __restrict__ CATb, const uint16_t* __restrict__ Wot,
    const float* __restrict__ bo, float* __restrict__ out)
{
    __shared__ __align__(16) uint16_t As[128][72];
    __shared__ __align__(16) uint16_t Bs[128][72];
    const int tid = threadIdx.x;
    const int n0 = blockIdx.x * 128;
    const int m0 = blockIdx.y * 128;
    const int lane = tid & 63, w = tid >> 6;
    const int wr = w >> 1, wc = w & 1;
    const int ll = lane & 15, quad = lane >> 4;

    const int ar = tid >> 1, ac = (tid & 1) * 32;
    const uint16_t* agp = &CATb[(size_t)(m0 + ar) * 1024 + ac];
    const uint16_t* bgp = &Wot[(size_t)(n0 + ar) * 1024 + ac];

    f32x4 acc[4][4];
    const f32x4 zz = {0.f, 0.f, 0.f, 0.f};
    #pragma unroll
    for (int i = 0; i < 4; ++i)
        #pragma unroll
        for (int j = 0; j < 4; ++j) acc[i][j] = zz;

    uint4 a0 = *(const uint4*)(agp);      uint4 a1 = *(const uint4*)(agp + 8);
    uint4 a2 = *(const uint4*)(agp + 16); uint4 a3 = *(const uint4*)(agp + 24);
    uint4 b0 = *(const uint4*)(bgp);      uint4 b1 = *(const uint4*)(bgp + 8);
    uint4 b2 = *(const uint4*)(bgp + 16); uint4 b3 = *(const uint4*)(bgp + 24);

    for (int k0 = 0; k0 < 1024; k0 += 64) {
        __syncthreads();
        *(uint4*)&As[ar][ac]      = a0;
        *(uint4*)&As[ar][ac + 8]  = a1;
        *(uint4*)&As[ar][ac + 16] = a2;
        *(uint4*)&As[ar][ac + 24] = a3;
        *(uint4*)&Bs[ar][ac]      = b0;
        *(uint4*)&Bs[ar][ac + 8]  = b1;
        *(uint4*)&Bs[ar][ac + 16] = b2;
        *(uint4*)&Bs[ar][ac + 24] = b3;
        __syncthreads();
        if (k0 + 64 < 1024) {
            const uint16_t* ag = agp + k0 + 64;
            const uint16_t* bg = bgp + k0 + 64;
            a0 = *(const uint4*)(ag);      a1 = *(const uint4*)(ag + 8);
            a2 = *(const uint4*)(ag + 16); a3 = *(const uint4*)(ag + 24);
            b0 = *(const uint4*)(bg);      b1 = *(const uint4*)(bg + 8);
            b2 = *(const uint4*)(bg + 16); b3 = *(const uint4*)(bg + 24);
        }
        #pragma unroll
        for (int ks = 0; ks < 2; ++ks) {
            bf16x8 af[4], bfv[4];
            #pragma unroll
            for (int mt = 0; mt < 4; ++mt)
                af[mt] = *(const bf16x8*)&As[wr * 64 + mt * 16 + ll][ks * 32 + quad * 8];
            #pragma unroll
            for (int nt = 0; nt < 4; ++nt)
                bfv[nt] = *(const bf16x8*)&Bs[wc * 64 + nt * 16 + ll][ks * 32 + quad * 8];
            #pragma unroll
            for (int mt = 0; mt < 4; ++mt)
                #pragma unroll
                for (int nt = 0; nt < 4; ++nt)
                    acc[mt][nt] = __builtin_amdgcn_mfma_f32_16x16x32_bf16(af[mt], bfv[nt], acc[mt][nt], 0, 0, 0);
        }
    }

    #pragma unroll
    for (int nt = 0; nt < 4; ++nt) {
        const int nl = wc * 64 + nt * 16 + ll;
        const float bval = bo[n0 + nl];
        #pragma unroll
        for (int mt = 0; mt < 4; ++mt) {
            #pragma unroll
            for (int r = 0; r < 4; ++r) {
                int m = m0 + wr * 64 + mt * 16 + quad * 4 + r;
                out[(size_t)m * 1024 + n0 + nl] = acc[mt][nt][r] + bval;
            }
        }
    }
}

extern "C" void kernel_launch(void* const* d_in, const int* in_sizes, int n_in,
                              void* d_out, int out_size, void* d_ws, size_t ws_size,
                              hipStream_t stream) {
    const float* x  = (const float*)d_in[0];
    const float* Wq = (const float*)d_in[1];
    const float* bq = (const float*)d_in[2];
    const float* Wk = (const float*)d_in[3];
    const float* bk = (const float*)d_in[4];
    const float* Wv = (const float*)d_in[5];
    const float* bv = (const float*)d_in[6];
    const float* Wo = (const float*)d_in[7];
    const float* bo = (const float*)d_in[8];

    uint8_t* p = (uint8_t*)d_ws;
    uint16_t* xb   = (uint16_t*)p; p += (size_t)M_ * D_ * 2;            // 16 MiB
    uint16_t* Wt   = (uint16_t*)p; p += (size_t)3 * H_ * DK_ * D_ * 2;  //  6 MiB
    uint16_t* Wot  = (uint16_t*)p; p += (size_t)D_ * D_ * 2;            //  2 MiB
    uint16_t* Qb   = (uint16_t*)p; p += (size_t)B_ * H_ * S_ * DK_ * 2; // 16 MiB
    uint16_t* Kb   = (uint16_t*)p; p += (size_t)B_ * H_ * S_ * DK_ * 2; // 16 MiB
    uint16_t* Vb   = (uint16_t*)p; p += (size_t)B_ * H_ * S_ * DK_ * 2; // 16 MiB (transposed [bh][dk][s])
    uint16_t* CATb = (uint16_t*)p;                                      // 16 MiB

    prep_kernel<<<dim3(4096 + 768 + 256), 256, 0, stream>>>(x, Wq, Wk, Wv, Wo, xb, Wt, Wot);
    qkv_mfma_kernel<<<dim3(24, M_ / 128), 256, 0, stream>>>(xb, Wt, bq, bk, bv, Qb, Kb, Vb);
    attn_mfma_kernel<<<dim3(8, B_ * H_), 256, 0, stream>>>(Qb, Kb, Vb, CATb);
    oproj_mfma_kernel<<<dim3(8, M_ / 128), 256, 0, stream>>>(CATb, Wot, bo, (float*)d_out);
}

// Round 12
// 257.794 us; speedup vs baseline: 1.0914x; 1.0914x over previous
//
#include <hip/hip_runtime.h>
#include <stdint.h>

#define B_  4
#define S_  2048
#define D_  1024
#define H_  16
#define DK_ 64
#define M_  (B_ * S_)

typedef __attribute__((ext_vector_type(8))) short bf16x8;
typedef __attribute__((ext_vector_type(4))) float f32x4;

// Q pre-scale: 1/sqrt(64) * log2(e)  (scores land in exp2 domain)
#define QSCALE 0.1803368801111204f

__device__ __forceinline__ uint16_t f2bf(float f) {
    uint32_t u = __builtin_bit_cast(uint32_t, f);
    u = (u + 0x7FFFu + ((u >> 16) & 1u)) >> 16;   // round-to-nearest-even
    return (uint16_t)u;
}

// pack two f32 -> bf16x2 (lo in low half), round-half-up, 3 VALU ops
__device__ __forceinline__ uint32_t pk2bf(float hi, float lo) {
    uint32_t a = __builtin_bit_cast(uint32_t, hi) + 0x8000u;
    uint32_t b = __builtin_bit_cast(uint32_t, lo) + 0x8000u;
    return __builtin_amdgcn_perm(a, b, 0x07060302u);
}

// direct global->LDS, 16 B per lane, wave-uniform LDS base (+ lane*16 by HW)
__device__ __forceinline__ void gload_lds16(const uint16_t* g, uint16_t* l) {
    __builtin_amdgcn_global_load_lds(
        (const __attribute__((address_space(1))) unsigned int*)g,
        (__attribute__((address_space(3))) unsigned int*)l,
        16, 0, 0);
}

// ---------------------------------------------------------------------------
// Fused prep: fp32->bf16 convert of x, transpose+convert of Wq/Wk/Wv, and
// transpose+convert of Wo — one launch, dispatched on blockIdx.x.
// ---------------------------------------------------------------------------
__global__ __launch_bounds__(256) void prep_kernel(
    const float* __restrict__ x,
    const float* __restrict__ Wq, const float* __restrict__ Wk,
    const float* __restrict__ Wv, const float* __restrict__ Wo,
    uint16_t* __restrict__ xb, uint16_t* __restrict__ Wt,
    uint16_t* __restrict__ Wot)
{
    __shared__ __align__(16) uint16_t tile[64][72];
    const int bid = blockIdx.x;
    const int t = threadIdx.x;

    if (bid < 4096) {              // ---- cvt x -> xb, 8 elems/thread
        int i = (bid * 256 + t) * 8;
        float4 a = *(const float4*)&x[i];
        float4 b = *(const float4*)&x[i + 4];
        uint16_t o[8] = {f2bf(a.x), f2bf(a.y), f2bf(a.z), f2bf(a.w),
                         f2bf(b.x), f2bf(b.y), f2bf(b.z), f2bf(b.w)};
        *(uint4*)&xb[i] = *(const uint4*)o;
        return;
    }

    const int lr = t >> 2, lc = (t & 3) * 16;
    const int oc = t >> 2, orr = (t & 3) * 16;

    if (bid < 4096 + 768) {        // ---- Wq/Wk/Wv: [1024][64] -> [dk][d] bf16
        const int zz = bid - 4096;
        const int z = zz >> 4, bx = zz & 15;       // z: 0..47 matrix, bx: d-tile
        const int sel = z >> 4, mat = z & 15;
        const float* base = (sel == 0) ? Wq : (sel == 1) ? Wk : Wv;
        const float* inm = base + (size_t)mat * 1024 * 64;
        uint16_t* outm = Wt + (size_t)z * 65536;
        const int r0 = bx * 64;
        uint16_t tmp[16];
        #pragma unroll
        for (int j = 0; j < 16; j += 4) {
            float4 v = *(const float4*)&inm[(size_t)(r0 + lr) * 64 + lc + j];
            tmp[j] = f2bf(v.x); tmp[j + 1] = f2bf(v.y); tmp[j + 2] = f2bf(v.z); tmp[j + 3] = f2bf(v.w);
        }
        *(uint4*)&tile[lr][lc]     = ((const uint4*)tmp)[0];
        *(uint4*)&tile[lr][lc + 8] = ((const uint4*)tmp)[1];
        __syncthreads();
        uint16_t ot[16];
        #pragma unroll
        for (int j = 0; j < 16; ++j) ot[j] = tile[orr + j][oc];
        *(uint4*)&outm[(size_t)oc * 1024 + r0 + orr]     = ((const uint4*)ot)[0];
        *(uint4*)&outm[(size_t)oc * 1024 + r0 + orr + 8] = ((const uint4*)ot)[1];
    } else {                       // ---- Wo: [1024][1024] -> [n][d] bf16
        const int zz = bid - 4864;
        const int bx = zz & 15, by = zz >> 4;
        const int r0 = bx * 64, c0 = by * 64;
        uint16_t tmp[16];
        #pragma unroll
        for (int j = 0; j < 16; j += 4) {
            float4 v = *(const float4*)&Wo[(size_t)(r0 + lr) * 1024 + c0 + lc + j];
            tmp[j] = f2bf(v.x); tmp[j + 1] = f2bf(v.y); tmp[j + 2] = f2bf(v.z); tmp[j + 3] = f2bf(v.w);
        }
        *(uint4*)&tile[lr][lc]     = ((const uint4*)tmp)[0];
        *(uint4*)&tile[lr][lc + 8] = ((const uint4*)tmp)[1];
        __syncthreads();
        uint16_t ot[16];
        #pragma unroll
        for (int j = 0; j < 16; ++j) ot[j] = tile[orr + j][oc];
        *(uint4*)&Wot[(size_t)(c0 + oc) * 1024 + r0 + orr]     = ((const uint4*)ot)[0];
        *(uint4*)&Wot[(size_t)(c0 + oc) * 1024 + r0 + orr + 8] = ((const uint4*)ot)[1];
    }
}

// ---------------------------------------------------------------------------
// QKV projection, MFMA. C[128 x 128] per block; 4 waves in 2x2, 64x64/wave.
// R10-proven structure: gload_lds staging (zero ds_writes), plain double-
// barrier per K-step, multi-block overlap (1536 blocks) + both-sides XOR
// swizzle:  LDS[r][chunk] = Global[r][chunk ^ (r&7)]   (source pre-swizzled)
//           read chunk    = (ks*4+quad) ^ (ll&7)       -> conflict-free
// LDS 32 KiB. Q pre-scaled by QSCALE. V transposed [bh][dk][s].
// ---------------------------------------------------------------------------
__global__ __launch_bounds__(256) void qkv_mfma_kernel(
    const uint16_t* __restrict__ xb, const uint16_t* __restrict__ Wt,
    const float* __restrict__ bq, const float* __restrict__ bk, const float* __restrict__ bv,
    uint16_t* __restrict__ Q, uint16_t* __restrict__ K, uint16_t* __restrict__ V)
{
    __shared__ __align__(16) uint16_t As[128][64];
    __shared__ __align__(16) uint16_t Bs[128][64];
    const int tid = threadIdx.x;
    const int nb = blockIdx.x;                  // 0..23
    const int sel = nb >> 3, npair = nb & 7;
    const int m0 = blockIdx.y * 128;
    const int lane = tid & 63, w = tid >> 6;
    const int wr = w >> 1, wc = w & 1;
    const int ll = lane & 15, quad = lane >> 4;

    const uint16_t* Bg = Wt + (size_t)nb * 128 * 1024;
    const float* bias = (sel == 0) ? bq : (sel == 1) ? bk : bv;

    // staging: wave w covers rows [w*32, w*32+32) via 4 issues of 8 rows.
    // lane: row += lane>>3, source chunk pre-swizzled (both-sides rule).
    const int srow = lane >> 3;                  // 0..7
    const int scg  = (lane & 7) ^ srow;          // pre-swizzled 16B chunk
    const uint16_t* agp = &xb[(size_t)(m0 + w * 32 + srow) * 1024 + scg * 8];
    const uint16_t* bgp = &Bg[(size_t)(w * 32 + srow) * 1024 + scg * 8];

    // read-side swizzled chunk (element offsets) for ks=0/1
    const int rc0 = ((0 * 4 + quad) ^ (ll & 7)) * 8;
    const int rc1 = ((1 * 4 + quad) ^ (ll & 7)) * 8;

    f32x4 acc[4][4];
    const f32x4 zz = {0.f, 0.f, 0.f, 0.f};
    #pragma unroll
    for (int i = 0; i < 4; ++i)
        #pragma unroll
        for (int j = 0; j < 4; ++j) acc[i][j] = zz;

    for (int k0 = 0; k0 < 1024; k0 += 64) {
        __syncthreads();                       // prior tile's reads done
        #pragma unroll
        for (int i = 0; i < 4; ++i) {
            gload_lds16(agp + (size_t)(i * 8) * 1024 + k0, &As[w * 32 + i * 8][0]);
            gload_lds16(bgp + (size_t)(i * 8) * 1024 + k0, &Bs[w * 32 + i * 8][0]);
        }
        __syncthreads();                       // staging visible (vmcnt drained)
        #pragma unroll
        for (int ks = 0; ks < 2; ++ks) {
            const int rc = ks ? rc1 : rc0;
            bf16x8 af[4], bfv[4];
            #pragma unroll
            for (int mt = 0; mt < 4; ++mt)
                af[mt] = *(const bf16x8*)&As[wr * 64 + mt * 16 + ll][rc];
            #pragma unroll
            for (int nt = 0; nt < 4; ++nt)
                bfv[nt] = *(const bf16x8*)&Bs[wc * 64 + nt * 16 + ll][rc];
            __builtin_amdgcn_s_setprio(1);
            #pragma unroll
            for (int mt = 0; mt < 4; ++mt)
                #pragma unroll
                for (int nt = 0; nt < 4; ++nt)
                    acc[mt][nt] = __builtin_amdgcn_mfma_f32_16x16x32_bf16(af[mt], bfv[nt], acc[mt][nt], 0, 0, 0);
            __builtin_amdgcn_s_setprio(0);
        }
    }

    if (sel == 2) {
        #pragma unroll
        for (int nt = 0; nt < 4; ++nt) {
            const int nl = wc * 64 + nt * 16 + ll;
            const int hh = npair * 2 + (nl >> 6);
            const int dk = nl & 63;
            const float bval = bias[npair * 128 + nl];
            #pragma unroll
            for (int mt = 0; mt < 4; ++mt) {
                int m = m0 + wr * 64 + mt * 16 + quad * 4;
                int b = m >> 11, s = m & 2047;
                uint2 pv;
                pv.x = pk2bf(acc[mt][nt][1] + bval, acc[mt][nt][0] + bval);
                pv.y = pk2bf(acc[mt][nt][3] + bval, acc[mt][nt][2] + bval);
                *(uint2*)&V[((size_t)(b * 16 + hh) * 64 + dk) * 2048 + s] = pv;
            }
        }
    } else {
        uint16_t* Out = (sel == 0) ? Q : K;
        const float qs = (sel == 0) ? QSCALE : 1.0f;
        #pragma unroll
        for (int nt = 0; nt < 4; ++nt) {
            const int nl = wc * 64 + nt * 16 + ll;
            const int hh = npair * 2 + (nl >> 6);
            const int dk = nl & 63;
            const float bval = bias[npair * 128 + nl];
            #pragma unroll
            for (int mt = 0; mt < 4; ++mt) {
                #pragma unroll
                for (int r = 0; r < 4; ++r) {
                    int m = m0 + wr * 64 + mt * 16 + quad * 4 + r;
                    int b = m >> 11, s = m & 2047;
                    float v = (acc[mt][nt][r] + bval) * qs;
                    Out[((size_t)(b * 16 + hh) * 2048 + s) * 64 + dk] = f2bf(v);
                }
            }
        }
    }
}

// ---------------------------------------------------------------------------
// Flash attention, MFMA, S^T = K·Q^T. 128-row q-blocks; block pairs q-tiles
// (15-p, p). KV tiles 128 wide, uniform trip counts, mask only on diagonal
// tile. K/V staged in LDS with T14 async-stage. PV in two 64-wide halves
// time-sharing Ps (wave-private). LDS 54,272 B. exp2-domain softmax.
// ---------------------------------------------------------------------------
__global__ __launch_bounds__(256) void attn_mfma_kernel(
    const uint16_t* __restrict__ Q, const uint16_t* __restrict__ K,
    const uint16_t* __restrict__ Vg, uint16_t* __restrict__ CAT)
{
    __shared__ __align__(16) uint16_t Ks[128][72];
    __shared__ __align__(16) uint16_t Vt[64][136];
    __shared__ __align__(16) uint16_t Ps[128][72];

    const int tid = threadIdx.x;
    const int lane = tid & 63, w = tid >> 6;
    const int ll = lane & 15, quad = lane >> 4;
    const int p = blockIdx.x;          // 0..7
    const int bh = blockIdx.y;
    const int b = bh >> 4, h = bh & 15;

    const uint16_t* Qbh = Q + (size_t)bh * S_ * 64;
    const uint16_t* Kbh = K + (size_t)bh * S_ * 64;
    const uint16_t* Vbh = Vg + (size_t)bh * 64 * S_;   // [dk][s]
    uint16_t* Cbh = CAT + (size_t)b * 2048 * 1024 + h * 64;

    // K staging: 2 threads/row, 64 B each
    const int ksr = tid >> 1, ksc = (tid & 1) * 32;
    // V staging: 4 threads/row, 64 B each
    const int vsr = tid >> 2, vsc = (tid & 3) * 32;
    const uint16_t* kgp = &Kbh[(size_t)ksr * 64 + ksc];       // + tb*64
    const uint16_t* vgp = &Vbh[(size_t)vsr * 2048 + vsc];     // + tb

    // ones B-fragment: B[k][0] = 1 -> row sums land in output col 0
    bf16x8 onesf;
    #pragma unroll
    for (int j = 0; j < 8; ++j) onesf[j] = (ll == 0) ? (short)0x3F80 : (short)0;

    const f32x4 zz = {0.f, 0.f, 0.f, 0.f};

    #pragma unroll 1
    for (int phase = 0; phase < 2; ++phase) {
        const int qtb = (phase == 0) ? (15 - p) : p;
        const int q0 = qtb * 128;
        const int qw = q0 + w * 32;     // this wave's q rows [qw, qw+32)

        bf16x8 qf[2][2];
        #pragma unroll
        for (int mt = 0; mt < 2; ++mt)
            #pragma unroll
            for (int ks = 0; ks < 2; ++ks)
                qf[mt][ks] = *(const bf16x8*)&Qbh[(size_t)(qw + mt * 16 + ll) * 64 + ks * 32 + quad * 8];

        f32x4 oacc[2][4];
        f32x4 lacc[2];
        #pragma unroll
        for (int i = 0; i < 2; ++i) {
            lacc[i] = zz;
            #pragma unroll
            for (int j = 0; j < 4; ++j) oacc[i][j] = zz;
        }

        const int nkt = qtb + 1;        // uniform across waves

        // prologue: tile 0 K/V loads into regs (global->reg, no LDS touch)
        uint4 kr0 = *(const uint4*)(kgp),      kr1 = *(const uint4*)(kgp + 8);
        uint4 kr2 = *(const uint4*)(kgp + 16), kr3 = *(const uint4*)(kgp + 24);
        uint4 vr0 = *(const uint4*)(vgp),      vr1 = *(const uint4*)(vgp + 8);
        uint4 vr2 = *(const uint4*)(vgp + 16), vr3 = *(const uint4*)(vgp + 24);

        #pragma unroll 1
        for (int kt = 0; kt < nkt; ++kt) {
            const int tb = kt * 128;
            __syncthreads();   // all waves done reading Ks/Vt of prior tile
            *(uint4*)&Ks[ksr][ksc]      = kr0;
            *(uint4*)&Ks[ksr][ksc + 8]  = kr1;
            *(uint4*)&Ks[ksr][ksc + 16] = kr2;
            *(uint4*)&Ks[ksr][ksc + 24] = kr3;
            *(uint4*)&Vt[vsr][vsc]      = vr0;
            *(uint4*)&Vt[vsr][vsc + 8]  = vr1;
            *(uint4*)&Vt[vsr][vsc + 16] = vr2;
            *(uint4*)&Vt[vsr][vsc + 24] = vr3;
            __syncthreads();

            if (kt + 1 < nkt) {     // issue next-tile loads early (overlap)
                const uint16_t* kg = kgp + (size_t)(tb + 128) * 64;
                const uint16_t* vg = vgp + tb + 128;
                kr0 = *(const uint4*)(kg);      kr1 = *(const uint4*)(kg + 8);
                kr2 = *(const uint4*)(kg + 16); kr3 = *(const uint4*)(kg + 24);
                vr0 = *(const uint4*)(vg);      vr1 = *(const uint4*)(vg + 8);
                vr2 = *(const uint4*)(vg + 16); vr3 = *(const uint4*)(vg + 24);
            }

            // S^T = K·Q^T  (M = t rows of K, N = q), 8 t-subtiles
            f32x4 sacc[8][2];
            #pragma unroll
            for (int i = 0; i < 8; ++i)
                #pragma unroll
                for (int j = 0; j < 2; ++j) sacc[i][j] = zz;
            #pragma unroll
            for (int ks = 0; ks < 2; ++ks) {
                #pragma unroll
                for (int tt = 0; tt < 8; ++tt) {
                    bf16x8 kf = *(const bf16x8*)&Ks[tt * 16 + ll][ks * 32 + quad * 8];
                    #pragma unroll
                    for (int mt = 0; mt < 2; ++mt)
                        sacc[tt][mt] = __builtin_amdgcn_mfma_f32_16x16x32_bf16(kf, qf[mt][ks], sacc[tt][mt], 0, 0, 0);
                }
            }

            // mask (diagonal tile only) + exp2
            const bool needMask = (kt == nkt - 1);
            #pragma unroll
            for (int mt = 0; mt < 2; ++mt) {
                const int qg = qw + mt * 16 + ll;
                #pragma unroll
                for (int tt = 0; tt < 8; ++tt) {
                    #pragma unroll
                    for (int r = 0; r < 4; ++r) {
                        float v = sacc[tt][mt][r];
                        if (needMask) {
                            int tg = tb + tt * 16 + quad * 4 + r;
                            v = (tg > qg) ? -1e30f : v;
                        }
                        sacc[tt][mt][r] = __builtin_amdgcn_exp2f(v);
                    }
                }
            }

            // PV in two 64-wide halves, time-sharing Ps (wave-private rows;
            // per-wave in-order DS pipeline makes pack->read->repack safe).
            #pragma unroll
            for (int half = 0; half < 2; ++half) {
                #pragma unroll
                for (int mt = 0; mt < 2; ++mt) {
                    #pragma unroll
                    for (int t4 = 0; t4 < 4; ++t4) {
                        const int tt = half * 4 + t4;
                        uint2 pv;
                        pv.x = pk2bf(sacc[tt][mt][1], sacc[tt][mt][0]);
                        pv.y = pk2bf(sacc[tt][mt][3], sacc[tt][mt][2]);
                        *(uint2*)&Ps[w * 32 + mt * 16 + ll][t4 * 16 + quad * 4] = pv;
                    }
                }
                #pragma unroll
                for (int ks2 = 0; ks2 < 2; ++ks2) {
                    bf16x8 pf[2], vf[4];
                    #pragma unroll
                    for (int mt = 0; mt < 2; ++mt)
                        pf[mt] = *(const bf16x8*)&Ps[w * 32 + mt * 16 + ll][ks2 * 32 + quad * 8];
                    #pragma unroll
                    for (int nt = 0; nt < 4; ++nt)
                        vf[nt] = *(const bf16x8*)&Vt[nt * 16 + ll][half * 64 + ks2 * 32 + quad * 8];
                    #pragma unroll
                    for (int mt = 0; mt < 2; ++mt) {
                        lacc[mt] = __builtin_amdgcn_mfma_f32_16x16x32_bf16(pf[mt], onesf, lacc[mt], 0, 0, 0);
                        #pragma unroll
                        for (int nt = 0; nt < 4; ++nt)
                            oacc[mt][nt] = __builtin_amdgcn_mfma_f32_16x16x32_bf16(pf[mt], vf[nt], oacc[mt][nt], 0, 0, 0);
                    }
                }
            }
        }

        // epilogue: l lives in lanes ll==0 (output col 0); broadcast within
        // each quad group via shfl, then scale + store
        #pragma unroll
        for (int mt = 0; mt < 2; ++mt) {
            f32x4 li;
            #pragma unroll
            for (int r = 0; r < 4; ++r)
                li[r] = 1.0f / __shfl(lacc[mt][r], lane & 48);
            #pragma unroll
            for (int r = 0; r < 4; ++r) {
                int q = qw + mt * 16 + quad * 4 + r;
                #pragma unroll
                for (int nt = 0; nt < 4; ++nt) {
                    float v = oacc[mt][nt][r] * li[r];
                    Cbh[(size_t)q * 1024 + nt * 16 + ll] = f2bf(v);
                }
            }
        }
        // next phase's first __syncthreads (top of kt loop) guards restaging
    }
}

// ---------------------------------------------------------------------------
// Output projection: out = CAT(bf16) @ Wo + bo, fp32 out. 128x128 tiles.
// R10-qkv structure ported: gload_lds staging (zero ds_writes), double-
// barrier per K-step, both-sides XOR swizzle, LDS 32 KiB linear [128][64].
// ---------------------------------------------------------------------------
__global__ __launch_bounds__(256) void oproj_mfma_kernel(
    const uint16_t* __restrict__ CATb, const uint16_t* __restrict__ Wot,
    const float* __restrict__ bo, float* __restrict__ out)
{
    __shared__ __align__(16) uint16_t As[128][64];
    __shared__ __align__(16) uint16_t Bs[128][64];
    const int tid = threadIdx.x;
    const int n0 = blockIdx.x * 128;
    const int m0 = blockIdx.y * 128;
    const int lane = tid & 63, w = tid >> 6;
    const int wr = w >> 1, wc = w & 1;
    const int ll = lane & 15, quad = lane >> 4;

    const int srow = lane >> 3;                  // 0..7
    const int scg  = (lane & 7) ^ srow;          // pre-swizzled 16B chunk
    const uint16_t* agp = &CATb[(size_t)(m0 + w * 32 + srow) * 1024 + scg * 8];
    const uint16_t* bgp = &Wot[(size_t)(n0 + w * 32 + srow) * 1024 + scg * 8];

    const int rc0 = ((0 * 4 + quad) ^ (ll & 7)) * 8;
    const int rc1 = ((1 * 4 + quad) ^ (ll & 7)) * 8;

    f32x4 acc[4][4];
    const f32x4 zz = {0.f, 0.f, 0.f, 0.f};
    #pragma unroll
    for (int i = 0; i < 4; ++i)
        #pragma unroll
        for (int j = 0; j < 4; ++j) acc[i][j] = zz;

    for (int k0 = 0; k0 < 1024; k0 += 64) {
        __syncthreads();                       // prior tile's reads done
        #pragma unroll
        for (int i = 0; i < 4; ++i) {
            gload_lds16(agp + (size_t)(i * 8) * 1024 + k0, &As[w * 32 + i * 8][0]);
            gload_lds16(bgp + (size_t)(i * 8) * 1024 + k0, &Bs[w * 32 + i * 8][0]);
        }
        __syncthreads();                       // staging visible
        #pragma unroll
        for (int ks = 0; ks < 2; ++ks) {
            const int rc = ks ? rc1 : rc0;
            bf16x8 af[4], bfv[4];
            #pragma unroll
            for (int mt = 0; mt < 4; ++mt)
                af[mt] = *(const bf16x8*)&As[wr * 64 + mt * 16 + ll][rc];
            #pragma unroll
            for (int nt = 0; nt < 4; ++nt)
                bfv[nt] = *(const bf16x8*)&Bs[wc * 64 + nt * 16 + ll][rc];
            __builtin_amdgcn_s_setprio(1);
            #pragma unroll
            for (int mt = 0; mt < 4; ++mt)
                #pragma unroll
                for (int nt = 0; nt < 4; ++nt)
                    acc[mt][nt] = __builtin_amdgcn_mfma_f32_16x16x32_bf16(af[mt], bfv[nt], acc[mt][nt], 0, 0, 0);
            __builtin_amdgcn_s_setprio(0);
        }
    }

    #pragma unroll
    for (int nt = 0; nt < 4; ++nt) {
        const int nl = wc * 64 + nt * 16 + ll;
        const float bval = bo[n0 + nl];
        #pragma unroll
        for (int mt = 0; mt < 4; ++mt) {
            #pragma unroll
            for (int r = 0; r < 4; ++r) {
                int m = m0 + wr * 64 + mt * 16 + quad * 4 + r;
                out[(size_t)m * 1024 + n0 + nl] = acc[mt][nt][r] + bval;
            }
        }
    }
}

extern "C" void kernel_launch(void* const* d_in, const int* in_sizes, int n_in,
                              void* d_out, int out_size, void* d_ws, size_t ws_size,
                              hipStream_t stream) {
    const float* x  = (const float*)d_in[0];
    const float* Wq = (const float*)d_in[1];
    const float* bq = (const float*)d_in[2];
    const float* Wk = (const float*)d_in[3];
    const float* bk = (const float*)d_in[4];
    const float* Wv = (const float*)d_in[5];
    const float* bv = (const float*)d_in[6];
    const float* Wo = (const float*)d_in[7];
    const float* bo = (const float*)d_in[8];

    uint8_t* p = (uint8_t*)d_ws;
    uint16_t* xb   = (uint16_t*)p; p += (size_t)M_ * D_ * 2;            // 16 MiB
    uint16_t* Wt   = (uint16_t*)p; p += (size_t)3 * H_ * DK_ * D_ * 2;  //  6 MiB
    uint16_t* Wot  = (uint16_t*)p; p += (size_t)D_ * D_ * 2;            //  2 MiB
    uint16_t* Qb   = (uint16_t*)p; p += (size_t)B_ * H_ * S_ * DK_ * 2; // 16 MiB
    uint16_t* Kb   = (uint16_t*)p; p += (size_t)B_ * H_ * S_ * DK_ * 2; // 16 MiB
    uint16_t* Vb   = (uint16_t*)p; p += (size_t)B_ * H_ * S_ * DK_ * 2; // 16 MiB (transposed [bh][dk][s])
    uint16_t* CATb = (uint16_t*)p;                                      // 16 MiB

    prep_kernel<<<dim3(4096 + 768 + 256), 256, 0, stream>>>(x, Wq, Wk, Wv, Wo, xb, Wt, Wot);
    qkv_mfma_kernel<<<dim3(24, M_ / 128), 256, 0, stream>>>(xb, Wt, bq, bk, bv, Qb, Kb, Vb);
    attn_mfma_kernel<<<dim3(8, B_ * H_), 256, 0, stream>>>(Qb, Kb, Vb, CATb);
    oproj_mfma_kernel<<<dim3(8, M_ / 128), 256, 0, stream>>>(CATb, Wot, bo, (float*)d_out);
}